// Round 6
// baseline (204.308 us; speedup 1.0000x reference)
//
#include <hip/hip_runtime.h>
#include <hip/hip_bf16.h>

typedef __attribute__((ext_vector_type(8))) short short8;
typedef __attribute__((ext_vector_type(4))) float floatx4;

#define B_SZ   32
#define L_IN   8192
#define C_INCH 64
#define KW     3
#define F_OUT  128
#define L_OUT  (L_IN - KW + 1)   // 8190
#define KDIM   (KW * C_INCH)     // 192

#define TILE_L  64
#define AROWS   (TILE_L + 2)     // 66
#define ASTRIDE 72               // 64 + 8 pad (bf16 buffer, conflict-free kloop)
#define TPB     4                // persistent: 1024 blocks = exactly 4/CU resident
#define NGRID   (B_SZ * (L_IN / TILE_L) / TPB)   // 1024

#define XCHUNKS (AROWS * 16)     // 1056 x 16B chunks of the fp32 tile (contiguous in x)
#define BUNITS  (AROWS * 8)      // 528 x 16B units of the bf16 tile

// W fragment table: 8 n-tiles x 6 k-steps x 64 lanes, one short8 (16B) each.
#define WTAB_ELEMS (8 * 6 * 64)  // 3072 -> 49152 bytes

// packed fp32x2 -> bf16x2 (RNE, emits v_cvt_pk_bf16_f32)
__device__ __forceinline__ unsigned pk2(float a, float b) {
    __hip_bfloat162 h = __float22bfloat162_rn(make_float2(a, b));
    unsigned u;
    __builtin_memcpy(&u, &h, 4);
    return u;
}

// R7 prep: pre-swizzle w (fp32 [192][128]) into bf16 MFMA fragment layout.
// wtab[(nt*6 + s)*64 + lane] holds W[k = s*32 + q*8 + j][f = nt*16 + nl].
__global__ __launch_bounds__(256) void w_prep(const float* __restrict__ w,
                                              short8* __restrict__ wtab) {
    int id = blockIdx.x * 256 + threadIdx.x;
    if (id >= WTAB_ELEMS) return;
    int lane = id & 63;
    int s    = (id >> 6) % 6;
    int nt   = id / 384;
    int nl = lane & 15, q = lane >> 4;
    const float* __restrict__ wf = w + nt * 16 + nl;
    float t[8];
#pragma unroll
    for (int j = 0; j < 8; ++j) t[j] = wf[(s * 32 + q * 8 + j) * F_OUT];
    union { unsigned u[4]; short8 v; } hb;
    hb.u[0] = pk2(t[0], t[1]);
    hb.u[1] = pk2(t[2], t[3]);
    hb.u[2] = pk2(t[4], t[5]);
    hb.u[3] = pk2(t[6], t[7]);
    wtab[id] = hb.v;
}

// R11: async-pipelined persistent blocks (T3/T4 pattern, plain HIP).
// R10 POST-MORTEM: NT stores cost +9us (sub-line HBM writes) -> dropped.
// Register-based TPB spilled (R8b) or lost occupancy (R9). This version
// pipelines with ZERO staging registers:
//   - x tile is a contiguous 16.9KB span -> global_load_lds (16B, linear
//     LDS dest, rule-21-safe) DMAs it into an fp32 LDS buffer.
//   - convert phase: LDS fp32 -> padded bf16 LDS (dense sweeps, cheap).
//   - raw s_barrier + manual waits: lgkmcnt(0) after convert; counted
//     vmcnt(8) (8 = epilogue stores; NEVER 0) at tile boundaries so tile
//     t+1's DMA flies under tile t's kloop+stores and stores drain across
//     tiles, not at every barrier. sched_barrier(0) pins VMEM issue order
//     so the vmcnt count is exact.
// OOB x rows (last tile of last batch) are clamped to the final row; they
// only feed outputs l >= L_OUT which are never stored.
template <bool PREP>
__global__ __launch_bounds__(256, 4) void conv1d_mfma(const float* __restrict__ x,
                                                      const float* __restrict__ w,
                                                      const float* __restrict__ bias,
                                                      float* __restrict__ out,
                                                      const short8* __restrict__ wtab) {
    __shared__ __align__(16) float a_raw[AROWS * C_INCH];   // 16896 B fp32 landing
    __shared__ __align__(16) short b_lds[AROWS * ASTRIDE];  //  9504 B bf16 padded

    const int tid  = threadIdx.x;
    const int lane = tid & 63;
    const int wave = tid >> 6;
    const int q    = lane >> 4;   // quad 0..3
    const int nl   = lane & 15;

    const int g      = blockIdx.x;
    const int b      = g >> 5;                     // 32 tile-groups per batch row
    const int l_base = (g & 31) * (TPB * TILE_L);  // 256-row span per block

    // ---- B fragments: 12 coalesced 16B loads from the prepped table ----
    short8 bfrag[6][2];
    if (PREP) {
#pragma unroll
        for (int n = 0; n < 2; ++n)
#pragma unroll
            for (int s = 0; s < 6; ++s)
                bfrag[s][n] = wtab[(((wave * 2 + n) * 6 + s) << 6) + lane];
    } else {
        // fallback (workspace too small): build in-kernel
#pragma unroll
        for (int n = 0; n < 2; ++n) {
            const int f = (wave * 2 + n) * 16 + nl;
            const float* __restrict__ wf = w + f;
#pragma unroll
            for (int s = 0; s < 6; ++s) {
                float t[8];
#pragma unroll
                for (int j = 0; j < 8; ++j)
                    t[j] = wf[(s * 32 + q * 8 + j) * F_OUT];
                union { unsigned u[4]; short8 v; } hb;
                hb.u[0] = pk2(t[0], t[1]);
                hb.u[1] = pk2(t[2], t[3]);
                hb.u[2] = pk2(t[4], t[5]);
                hb.u[3] = pk2(t[6], t[7]);
                bfrag[s][n] = hb.v;
            }
        }
    }

    // bias: swapped C/D layout -> lane holds f = base + q*4 + r -> float4
    float4 bv[2];
#pragma unroll
    for (int n = 0; n < 2; ++n)
        bv[n] = *(const float4*)(bias + (wave * 2 + n) * 16 + q * 4);

    // async DMA of one fp32 tile (rows l0..l0+65, all 64 ch = contiguous span)
    auto stage = [&](int l0) {
#pragma unroll
        for (int r = 0; r < 5; ++r) {
            int c = r * 256 + tid;                 // 16B chunk index, < 1056
            if (c < XCHUNKS) {
                int row  = c >> 4;
                int pc   = c & 15;
                int grow = b * L_IN + l0 + row;    // clamp: OOB rows only feed
                grow = grow < (B_SZ * L_IN - 1) ?  //        non-stored outputs
                       grow : (B_SZ * L_IN - 1);
                const float* src = x + (size_t)grow * C_INCH + pc * 4;
                // wave-uniform LDS base; HW adds lane*16
                float* dst = &a_raw[(r * 256 + wave * 64) * 4];
                __builtin_amdgcn_global_load_lds(
                    (const __attribute__((address_space(1))) void*)src,
                    (__attribute__((address_space(3))) void*)dst, 16, 0, 0);
            }
        }
    };

    // ---- prologue: stage tile 0, full drain (only place vmcnt hits 0) ----
    stage(l_base);
    __syncthreads();

#pragma unroll
    for (int t = 0; t < TPB; ++t) {
        const int l0 = l_base + t * TILE_L;

        // ---- convert: LDS fp32 -> padded bf16 LDS ----
#pragma unroll
        for (int r = 0; r < 3; ++r) {
            int u = r * 256 + tid;                 // 16B bf16 unit, < 528
            if (u < BUNITS) {
                int p = u >> 3, cb = u & 7;
                const floatx4* ap = (const floatx4*)&a_raw[p * C_INCH + cb * 8];
                floatx4 a0 = ap[0], a1 = ap[1];
                union { unsigned uu[4]; short8 v; } h;
                h.uu[0] = pk2(a0[0], a0[1]);
                h.uu[1] = pk2(a0[2], a0[3]);
                h.uu[2] = pk2(a1[0], a1[1]);
                h.uu[3] = pk2(a1[2], a1[3]);
                *(short8*)&b_lds[p * ASTRIDE + cb * 8] = h.v;
            }
        }
        asm volatile("s_waitcnt lgkmcnt(0)" ::: "memory");  // ds_writes visible
        __builtin_amdgcn_s_barrier();                       // b ready, a consumed

        // ---- issue next tile's DMA: flies under kloop + stores ----
        if (t + 1 < TPB) {
            stage(l0 + TILE_L);
            __builtin_amdgcn_sched_barrier(0);  // pin: no store hoists above DMA
        }

        // ---- K-loop: 6 steps of 32; 4 m x 2 n per wave (swapped operands) ----
        floatx4 acc[4][2];
#pragma unroll
        for (int m = 0; m < 4; ++m)
#pragma unroll
            for (int n = 0; n < 2; ++n) acc[m][n] = (floatx4){0.f, 0.f, 0.f, 0.f};

#pragma unroll
        for (int s = 0; s < 6; ++s) {
#pragma unroll
            for (int m = 0; m < 4; ++m) {
                short8 af = *(const short8*)&b_lds[(m * 16 + nl + (s >> 1)) * ASTRIDE
                                                   + (s & 1) * 32 + q * 8];
#pragma unroll
                for (int n = 0; n < 2; ++n)
                    acc[m][n] = __builtin_amdgcn_mfma_f32_16x16x32_bf16(
                        bfrag[s][n], af, acc[m][n], 0, 0, 0);
            }
        }

        // ---- epilogue: lane(nl,q) holds f = base+q*4+r, l = l0+m*16+nl ----
#pragma unroll
        for (int n = 0; n < 2; ++n) {
            const int fb = (wave * 2 + n) * 16 + q * 4;
#pragma unroll
            for (int m = 0; m < 4; ++m) {
                const int l = l0 + m * 16 + nl;
                if (l < L_OUT) {
                    float4 v;
                    v.x = acc[m][n][0] + bv[n].x;
                    v.y = acc[m][n][1] + bv[n].y;
                    v.z = acc[m][n][2] + bv[n].z;
                    v.w = acc[m][n][3] + bv[n].w;
                    v.x = v.x > 0.f ? v.x : 0.f;
                    v.y = v.y > 0.f ? v.y : 0.f;
                    v.z = v.z > 0.f ? v.z : 0.f;
                    v.w = v.w > 0.f ? v.w : 0.f;
                    *(float4*)(out + ((size_t)b * L_OUT + l) * F_OUT + fb) = v;
                }
            }
        }

        // ---- tile boundary: counted wait — 8 newest VMEM ops are our stores,
        //      so vmcnt(8) proves the (older) DMA for t+1 landed; stores keep
        //      draining in the background. Never vmcnt(0) in the loop. ----
        if (t + 1 < TPB) {
            asm volatile("s_waitcnt vmcnt(8)" ::: "memory");
            __builtin_amdgcn_s_barrier();
        }
    }
}

extern "C" void kernel_launch(void* const* d_in, const int* in_sizes, int n_in,
                              void* d_out, int out_size, void* d_ws, size_t ws_size,
                              hipStream_t stream) {
    const float* x    = (const float*)d_in[0];
    const float* w    = (const float*)d_in[1];
    const float* bias = (const float*)d_in[2];
    float* out        = (float*)d_out;

    if (d_ws != nullptr && ws_size >= (size_t)WTAB_ELEMS * sizeof(short8)) {
        short8* wtab = (short8*)d_ws;
        w_prep<<<dim3((WTAB_ELEMS + 255) / 256), 256, 0, stream>>>(w, wtab);
        conv1d_mfma<true><<<dim3(NGRID), 256, 0, stream>>>(x, w, bias, out, wtab);
    } else {
        conv1d_mfma<false><<<dim3(NGRID), 256, 0, stream>>>(x, w, bias, out, nullptr);
    }
}

// Round 7
// 193.103 us; speedup vs baseline: 1.0580x; 1.0580x over previous
//
#include <hip/hip_runtime.h>
#include <hip/hip_bf16.h>

typedef __attribute__((ext_vector_type(8))) short short8;
typedef __attribute__((ext_vector_type(4))) float floatx4;

#define B_SZ   32
#define L_IN   8192
#define C_INCH 64
#define KW     3
#define F_OUT  128
#define L_OUT  (L_IN - KW + 1)   // 8190
#define KDIM   (KW * C_INCH)     // 192

#define TILE_L  64
#define AROWS   (TILE_L + 2)     // 66
#define NGRID   (B_SZ * (L_IN / TILE_L))   // 4096 blocks, TPB=1 (proven best grid)

#define XCHUNKS (AROWS * 16)     // 1056 x 16B chunks of the fp32 tile

// W fragment table: 8 n-tiles x 6 k-steps x 64 lanes, one short8 (16B) each.
#define WTAB_ELEMS (8 * 6 * 64)  // 3072 -> 49152 bytes

// packed fp32x2 -> bf16x2 (RNE, emits v_cvt_pk_bf16_f32)
__device__ __forceinline__ unsigned pk2(float a, float b) {
    __hip_bfloat162 h = __float22bfloat162_rn(make_float2(a, b));
    unsigned u;
    __builtin_memcpy(&u, &h, 4);
    return u;
}

// R7 prep: pre-swizzle w (fp32 [192][128]) into bf16 MFMA fragment layout.
// wtab[(nt*6 + s)*64 + lane] holds W[k = s*32 + q*8 + j][f = nt*16 + nl].
__global__ __launch_bounds__(256) void w_prep(const float* __restrict__ w,
                                              short8* __restrict__ wtab) {
    int id = blockIdx.x * 256 + threadIdx.x;
    if (id >= WTAB_ELEMS) return;
    int lane = id & 63;
    int s    = (id >> 6) % 6;
    int nt   = id / 384;
    int nl = lane & 15, q = lane >> 4;
    const float* __restrict__ wf = w + nt * 16 + nl;
    float t[8];
#pragma unroll
    for (int j = 0; j < 8; ++j) t[j] = wf[(s * 32 + q * 8 + j) * F_OUT];
    union { unsigned u[4]; short8 v; } hb;
    hb.u[0] = pk2(t[0], t[1]);
    hb.u[1] = pk2(t[2], t[3]);
    hb.u[2] = pk2(t[4], t[5]);
    hb.u[3] = pk2(t[6], t[7]);
    wtab[id] = hb.v;
}

// R12: R1's proven grid (TPB=1, 4096 blocks, occ 4) + zero-register async
// staging. R11 POST-MORTEM: its regression (~72us) was the 1024-block
// persistent grid + double-LDS round trip, not the DMA itself (which passed
// correctness). Here:
//  - x tile (contiguous 16.9KB fp32 span) DMA'd via global_load_lds into a
//    single LINEAR fp32 LDS buffer. No staging VGPRs, no per-thread vmcnt
//    chains, no cvt/ds_write phase, one __syncthreads total.
//  - fp32 row stride 256B == 0 mod 128 would be a 16-way bank conflict on
//    the kloop reads -> rule-21 source-side XOR swizzle: LDS stays linear,
//    DMA lane fetches chunk (pc ^ (row&7)) of its row (same 256B segment ->
//    coalescing unchanged); kloop reads with the same XOR -> 2-way only.
//  - convert fp32->bf16 in the kloop (4 cvt_pk per fragment; VALU is 10%
//    busy, plenty of headroom).
// OOB rows (tile end of last batch) clamp to the last x row; they only feed
// outputs l >= L_OUT which are never stored.
template <bool PREP>
__global__ __launch_bounds__(256, 4) void conv1d_mfma(const float* __restrict__ x,
                                                      const float* __restrict__ w,
                                                      const float* __restrict__ bias,
                                                      float* __restrict__ out,
                                                      const short8* __restrict__ wtab) {
    __shared__ __align__(16) float a_raw[AROWS * C_INCH];  // 16896 B, linear

    const int tid  = threadIdx.x;
    const int lane = tid & 63;
    const int wave = tid >> 6;
    const int q    = lane >> 4;   // quad 0..3
    const int nl   = lane & 15;

    const int g  = blockIdx.x;
    const int b  = g >> 7;              // 128 tiles per batch row
    const int l0 = (g & 127) * TILE_L;

    // ---- B fragments: 12 coalesced 16B loads from the prepped table ----
    short8 bfrag[6][2];
    if (PREP) {
#pragma unroll
        for (int n = 0; n < 2; ++n)
#pragma unroll
            for (int s = 0; s < 6; ++s)
                bfrag[s][n] = wtab[(((wave * 2 + n) * 6 + s) << 6) + lane];
    } else {
        // fallback (workspace too small): build in-kernel
#pragma unroll
        for (int n = 0; n < 2; ++n) {
            const int f = (wave * 2 + n) * 16 + nl;
            const float* __restrict__ wf = w + f;
#pragma unroll
            for (int s = 0; s < 6; ++s) {
                float t[8];
#pragma unroll
                for (int j = 0; j < 8; ++j)
                    t[j] = wf[(s * 32 + q * 8 + j) * F_OUT];
                union { unsigned u[4]; short8 v; } hb;
                hb.u[0] = pk2(t[0], t[1]);
                hb.u[1] = pk2(t[2], t[3]);
                hb.u[2] = pk2(t[4], t[5]);
                hb.u[3] = pk2(t[6], t[7]);
                bfrag[s][n] = hb.v;
            }
        }
    }

    // bias: swapped C/D layout -> lane holds f = base + q*4 + r -> float4
    float4 bv[2];
#pragma unroll
    for (int n = 0; n < 2; ++n)
        bv[n] = *(const float4*)(bias + (wave * 2 + n) * 16 + q * 4);

    // ---- async DMA stage: 1056 x 16B chunks, swizzled SOURCE, linear dest.
    //      Chunk at LDS position (row*16 + pc) holds x chunk (pc ^ (row&7)).
#pragma unroll
    for (int r = 0; r < 5; ++r) {
        int c = r * 256 + tid;
        if (c < XCHUNKS) {
            int row = c >> 4;
            int pc  = c & 15;
            int spc = pc ^ (row & 7);              // source chunk within row
            int grow = b * L_IN + l0 + row;        // clamp: OOB rows only feed
            grow = grow < (B_SZ * L_IN - 1) ?      //        non-stored outputs
                   grow : (B_SZ * L_IN - 1);
            const float* src = x + (size_t)grow * C_INCH + spc * 4;
            // wave-uniform LDS base; HW adds lane*16
            float* dst = &a_raw[(r * 256 + wave * 64) * 4];
            __builtin_amdgcn_global_load_lds(
                (const __attribute__((address_space(1))) void*)src,
                (__attribute__((address_space(3))) void*)dst, 16, 0, 0);
        }
    }
    __syncthreads();   // drains vmcnt (covers global_load_lds) + barrier

    // ---- K-loop: 6 steps of 32; 4 m x 2 n per wave (swapped operands).
    //      A-fragment: 8 consecutive fp32 = 2 swizzled 16B chunks ->
    //      2x ds_read_b128 + 4x cvt_pk. 2-way bank aliasing only (free).
    floatx4 acc[4][2];
#pragma unroll
    for (int m = 0; m < 4; ++m)
#pragma unroll
        for (int n = 0; n < 2; ++n) acc[m][n] = (floatx4){0.f, 0.f, 0.f, 0.f};

#pragma unroll
    for (int s = 0; s < 6; ++s) {
#pragma unroll
        for (int m = 0; m < 4; ++m) {
            const int row = m * 16 + nl + (s >> 1);
            const int fxr = row & 7;
            const int pc0 = (s & 1) * 8 + q * 2;   // even
            floatx4 c0 = *(const floatx4*)&a_raw[row * C_INCH + (pc0 ^ fxr) * 4];
            floatx4 c1 = *(const floatx4*)&a_raw[row * C_INCH + ((pc0 + 1) ^ fxr) * 4];
            union { unsigned u[4]; short8 v; } h;
            h.u[0] = pk2(c0[0], c0[1]);
            h.u[1] = pk2(c0[2], c0[3]);
            h.u[2] = pk2(c1[0], c1[1]);
            h.u[3] = pk2(c1[2], c1[3]);
#pragma unroll
            for (int n = 0; n < 2; ++n)
                acc[m][n] = __builtin_amdgcn_mfma_f32_16x16x32_bf16(
                    bfrag[s][n], h.v, acc[m][n], 0, 0, 0);
        }
    }

    // ---- epilogue: lane(nl,q) holds f = base+q*4+r (r=0..3), l = l0+m*16+nl
    //      -> one float4 store per (m,n) ----
#pragma unroll
    for (int n = 0; n < 2; ++n) {
        const int fb = (wave * 2 + n) * 16 + q * 4;
#pragma unroll
        for (int m = 0; m < 4; ++m) {
            const int l = l0 + m * 16 + nl;
            if (l < L_OUT) {
                float4 v;
                v.x = acc[m][n][0] + bv[n].x;
                v.y = acc[m][n][1] + bv[n].y;
                v.z = acc[m][n][2] + bv[n].z;
                v.w = acc[m][n][3] + bv[n].w;
                v.x = v.x > 0.f ? v.x : 0.f;
                v.y = v.y > 0.f ? v.y : 0.f;
                v.z = v.z > 0.f ? v.z : 0.f;
                v.w = v.w > 0.f ? v.w : 0.f;
                *(float4*)(out + ((size_t)b * L_OUT + l) * F_OUT + fb) = v;
            }
        }
    }
}

extern "C" void kernel_launch(void* const* d_in, const int* in_sizes, int n_in,
                              void* d_out, int out_size, void* d_ws, size_t ws_size,
                              hipStream_t stream) {
    const float* x    = (const float*)d_in[0];
    const float* w    = (const float*)d_in[1];
    const float* bias = (const float*)d_in[2];
    float* out        = (float*)d_out;

    if (d_ws != nullptr && ws_size >= (size_t)WTAB_ELEMS * sizeof(short8)) {
        short8* wtab = (short8*)d_ws;
        w_prep<<<dim3((WTAB_ELEMS + 255) / 256), 256, 0, stream>>>(w, wtab);
        conv1d_mfma<true><<<dim3(NGRID), 256, 0, stream>>>(x, w, bias, out, wtab);
    } else {
        conv1d_mfma<false><<<dim3(NGRID), 256, 0, stream>>>(x, w, bias, out, nullptr);
    }
}